// Round 1
// baseline (4705.022 us; speedup 1.0000x reference)
//
#include <hip/hip_runtime.h>

typedef _Float16 f16x2 __attribute__((ext_vector_type(2)));

#define NB 256   // batch
#define NT 512   // time
#define NI 64    // input
#define NH 256   // hidden

#define WHH_N (3*128*256)   // 98304 f16x2 = 384 KB
#define WIH_N (3*32*256)    // 24576 f16x2 = 96 KB

// ---------------- weight prep: fp32 -> f16x2, lane-coalesced layouts ----------------
// whh_p[(g*128+c)*256 + j] = { w_hh[(g*256+j)*256 + 2c], w_hh[...+2c+1] }
// wih_p[(g*32 +c)*256 + j] = { w_ih[(g*256+j)*64  + 2c], w_ih[...+2c+1] }
__global__ __launch_bounds__(256) void gru_prep_kernel(
    const float* __restrict__ w_ih, const float* __restrict__ w_hh,
    f16x2* __restrict__ whh_p, f16x2* __restrict__ wih_p)
{
  int n = blockIdx.x * 256 + threadIdx.x;
  if (n < WHH_N) {
    int g = n >> 15, rem = n & 32767, c = rem >> 8, j = rem & 255;
    const float* src = w_hh + (g*256 + j)*256 + 2*c;
    whh_p[n] = f16x2{(_Float16)src[0], (_Float16)src[1]};
  } else if (n < WHH_N + WIH_N) {
    int m = n - WHH_N;
    int g = m >> 13, rem = m & 8191, c = rem >> 8, j = rem & 255;
    const float* src = w_ih + (g*256 + j)*64 + 2*c;
    wih_p[m] = f16x2{(_Float16)src[0], (_Float16)src[1]};
  }
}

__device__ __forceinline__ float sigm(float v) {
  return __builtin_amdgcn_rcpf(1.0f + __expf(-v));
}
__device__ __forceinline__ float tanh_f(float v) {
  // 1 - 2/(1+e^{2v}): correct limits at +/-inf, no inf/inf
  return 1.0f - 2.0f * __builtin_amdgcn_rcpf(1.0f + __expf(2.0f * v));
}

// ---------------- persistent recurrent kernel: 1 block = 1 sequence ----------------
__global__ __launch_bounds__(256, 1) void gru_kernel(
    const float* __restrict__ x,      // [B, T, I]
    const float* __restrict__ b_ih,   // [768]
    const float* __restrict__ b_hh,   // [768]
    const float* __restrict__ w_out,  // [256]
    const float* __restrict__ b_out,  // [1]
    const f16x2* __restrict__ whh_p,
    const f16x2* __restrict__ wih_p,
    float* __restrict__ out)          // [T, B]
{
  __shared__ __align__(16) f16x2 h_lds[2][128];   // double-buffered h (f16)
  __shared__ __align__(16) f16x2 x_lds[4][32];    // 4 timesteps of x (f16)
  __shared__ float red[2][4];                      // out-reduction partials
  __shared__ f16x2 wih_lds[WIH_N];                 // 96 KB

  const int b  = blockIdx.x;
  const int j  = threadIdx.x;       // hidden index owned by this lane
  const int wv = j >> 6;            // wave id (0..3)

  // stage w_ih into LDS (coalesced, once)
  for (int n = j; n < WIH_N; n += 256) wih_lds[n] = wih_p[n];

  // w_hh rows {j, 256+j, 512+j} -> persistent registers (384 VGPRs)
  f16x2 w0[128], w1[128], w2[128];
  #pragma unroll
  for (int c = 0; c < 128; ++c) w0[c] = whh_p[(0*128 + c)*256 + j];
  #pragma unroll
  for (int c = 0; c < 128; ++c) w1[c] = whh_p[(1*128 + c)*256 + j];
  #pragma unroll
  for (int c = 0; c < 128; ++c) w2[c] = whh_p[(2*128 + c)*256 + j];

  const float bih0 = b_ih[j], bih1 = b_ih[256 + j], bih2 = b_ih[512 + j];
  const float bhh0 = b_hh[j], bhh1 = b_hh[256 + j], bhh2 = b_hh[512 + j];
  const float wo = w_out[j];
  const float bo = b_out[0];

  if (j < 128) h_lds[0][j] = f16x2{(_Float16)0.0f, (_Float16)0.0f};
  float h = 0.0f;

  const float* xb = x + (size_t)b * (NT * NI);
  __syncthreads();

  for (int tc = 0; tc < NT/4; ++tc) {
    // ---- stage x for 4 timesteps: 256 floats, one per thread; flat f16 idx == j ----
    {
      float xv = xb[tc*256 + j];
      ((_Float16*)x_lds)[j] = (_Float16)xv;
    }
    __syncthreads();

    // ---- gi for 4 future steps (amortizes w_ih LDS reads 4x) ----
    float gi0[4] = {bih0, bih0, bih0, bih0};
    float gi1[4] = {bih1, bih1, bih1, bih1};
    float gi2[4] = {bih2, bih2, bih2, bih2};
    #pragma unroll
    for (int cb = 0; cb < 4; ++cb) {
      f16x2 xr[4][8];
      #pragma unroll
      for (int k = 0; k < 4; ++k) {
        float4 p0 = ((const float4*)&x_lds[k][cb*8])[0];
        float4 p1 = ((const float4*)&x_lds[k][cb*8])[1];
        xr[k][0] = __builtin_bit_cast(f16x2, p0.x);
        xr[k][1] = __builtin_bit_cast(f16x2, p0.y);
        xr[k][2] = __builtin_bit_cast(f16x2, p0.z);
        xr[k][3] = __builtin_bit_cast(f16x2, p0.w);
        xr[k][4] = __builtin_bit_cast(f16x2, p1.x);
        xr[k][5] = __builtin_bit_cast(f16x2, p1.y);
        xr[k][6] = __builtin_bit_cast(f16x2, p1.z);
        xr[k][7] = __builtin_bit_cast(f16x2, p1.w);
      }
      #pragma unroll
      for (int ci = 0; ci < 8; ++ci) {
        const int c = cb*8 + ci;
        f16x2 a0 = wih_lds[(0*32 + c)*256 + j];
        f16x2 a1 = wih_lds[(1*32 + c)*256 + j];
        f16x2 a2 = wih_lds[(2*32 + c)*256 + j];
        #pragma unroll
        for (int k = 0; k < 4; ++k) {
          gi0[k] = __builtin_amdgcn_fdot2(a0, xr[k][ci], gi0[k], false);
          gi1[k] = __builtin_amdgcn_fdot2(a1, xr[k][ci], gi1[k], false);
          gi2[k] = __builtin_amdgcn_fdot2(a2, xr[k][ci], gi2[k], false);
        }
      }
    }

    // ---- 4 recurrent steps ----
    #pragma unroll
    for (int k = 0; k < 4; ++k) {
      const int t = tc*4 + k;
      const f16x2* hb = h_lds[k & 1];
      float r0 = bhh0, r1 = 0.0f;
      float z0 = bhh1, z1 = 0.0f;
      float n0 = bhh2, n1 = 0.0f;
      #pragma unroll
      for (int m = 0; m < 32; ++m) {
        float4 hv = ((const float4*)hb)[m];   // broadcast ds_read_b128: 8 f16 of h
        f16x2 h0 = __builtin_bit_cast(f16x2, hv.x);
        f16x2 h1 = __builtin_bit_cast(f16x2, hv.y);
        f16x2 h2 = __builtin_bit_cast(f16x2, hv.z);
        f16x2 h3 = __builtin_bit_cast(f16x2, hv.w);
        r0 = __builtin_amdgcn_fdot2(w0[4*m+0], h0, r0, false);
        z0 = __builtin_amdgcn_fdot2(w1[4*m+0], h0, z0, false);
        n0 = __builtin_amdgcn_fdot2(w2[4*m+0], h0, n0, false);
        r1 = __builtin_amdgcn_fdot2(w0[4*m+1], h1, r1, false);
        z1 = __builtin_amdgcn_fdot2(w1[4*m+1], h1, z1, false);
        n1 = __builtin_amdgcn_fdot2(w2[4*m+1], h1, n1, false);
        r0 = __builtin_amdgcn_fdot2(w0[4*m+2], h2, r0, false);
        z0 = __builtin_amdgcn_fdot2(w1[4*m+2], h2, z0, false);
        n0 = __builtin_amdgcn_fdot2(w2[4*m+2], h2, n0, false);
        r1 = __builtin_amdgcn_fdot2(w0[4*m+3], h3, r1, false);
        z1 = __builtin_amdgcn_fdot2(w1[4*m+3], h3, z1, false);
        n1 = __builtin_amdgcn_fdot2(w2[4*m+3], h3, n1, false);
      }
      float rr = sigm(gi0[k] + r0 + r1);
      float zz = sigm(gi1[k] + z0 + z1);
      float nn = tanh_f(gi2[k] + rr * (n0 + n1));
      h = (1.0f - zz) * nn + zz * h;

      // publish h (f16) to the other buffer
      ((_Float16*)h_lds[(k + 1) & 1])[j] = (_Float16)h;

      // output projection: block-wide reduction of h*w_out
      float p = h * wo;
      p += __shfl_down(p, 32);
      p += __shfl_down(p, 16);
      p += __shfl_down(p, 8);
      p += __shfl_down(p, 4);
      p += __shfl_down(p, 2);
      p += __shfl_down(p, 1);
      if ((j & 63) == 0) red[t & 1][wv] = p;
      __syncthreads();
      if (j == 0) {
        out[t*NB + b] = red[t & 1][0] + red[t & 1][1] + red[t & 1][2] + red[t & 1][3] + bo;
      }
    }
  }
}

extern "C" void kernel_launch(void* const* d_in, const int* in_sizes, int n_in,
                              void* d_out, int out_size, void* d_ws, size_t ws_size,
                              hipStream_t stream) {
  const float* x     = (const float*)d_in[0];
  const float* w_ih  = (const float*)d_in[1];
  const float* w_hh  = (const float*)d_in[2];
  const float* b_ih  = (const float*)d_in[3];
  const float* b_hh  = (const float*)d_in[4];
  const float* w_out = (const float*)d_in[5];
  const float* b_out = (const float*)d_in[6];
  float* out = (float*)d_out;

  f16x2* whh_p = (f16x2*)d_ws;          // 384 KB
  f16x2* wih_p = whh_p + WHH_N;         // 96 KB  (total ws use: 480 KB)

  gru_prep_kernel<<<480, 256, 0, stream>>>(w_ih, w_hh, whh_p, wih_p);
  gru_kernel<<<NB, 256, 0, stream>>>(x, b_ih, b_hh, w_out, b_out, whh_p, wih_p, out);
}

// Round 2
// 3693.124 us; speedup vs baseline: 1.2740x; 1.2740x over previous
//
#include <hip/hip_runtime.h>

typedef _Float16 f16x2 __attribute__((ext_vector_type(2)));

#define NB 256   // batch
#define NT 512   // time
#define NI 64    // input
#define NH 256   // hidden

// w_hh packed: slab = g*2+half (6 slabs), each slab [64 c][256 j] f16x2
#define WHH_N (6*64*256)     // 98304 f16x2 = 384 KB
// w_ih packed for b128 LDS reads: [(g*8+cq)][256 j][4 cc] f16x2
#define WIH_N (3*8*256*4)    // 24576 f16x2 = 96 KB

// ---------------- weight prep: fp32 -> f16x2, lane/b128-friendly layouts ----------------
__global__ __launch_bounds__(256) void gru_prep_kernel(
    const float* __restrict__ w_ih, const float* __restrict__ w_hh,
    f16x2* __restrict__ whh_p, f16x2* __restrict__ wih_p)
{
  int n = blockIdx.x * 256 + threadIdx.x;
  if (n < WHH_N) {
    int slab = n >> 14, c = (n >> 8) & 63, j = n & 255;
    int g = slab >> 1, half = slab & 1;
    const float* src = w_hh + (g * 256 + j) * 256 + half * 128 + 2 * c;
    whh_p[n] = f16x2{(_Float16)src[0], (_Float16)src[1]};
  } else if (n < WHH_N + WIH_N) {
    int m = n - WHH_N;
    int cc = m & 3, j = (m >> 2) & 255, cq = (m >> 10) & 7, g = m >> 13;
    int c = cq * 4 + cc;
    const float* src = w_ih + (g * 256 + j) * 64 + 2 * c;
    wih_p[m] = f16x2{(_Float16)src[0], (_Float16)src[1]};
  }
}

__device__ __forceinline__ float sigm(float v) {
  return __builtin_amdgcn_rcpf(1.0f + __expf(-v));
}
__device__ __forceinline__ float tanh_f(float v) {
  return 1.0f - 2.0f * __builtin_amdgcn_rcpf(1.0f + __expf(2.0f * v));
}

// ---------------- persistent recurrent kernel: 1 block = 1 sequence ----------------
// 512 threads: thread (j = tid&255, half = tid>>8) computes the `half` 128-wide
// slice of the 3 gate dots for hidden unit j. 192 f16x2 weight VGPRs per lane.
__global__ __launch_bounds__(512, 2) void gru_kernel(
    const float* __restrict__ x,      // [B, T, I]
    const float* __restrict__ b_ih,   // [768]
    const float* __restrict__ b_hh,   // [768]
    const float* __restrict__ w_out,  // [256]
    const float* __restrict__ b_out,  // [1]
    const f16x2* __restrict__ whh_p,
    const f16x2* __restrict__ wih_p,
    float* __restrict__ out)          // [T, B]
{
  __shared__ __align__(16) f16x2 wih_lds[WIH_N];   // 96 KB
  __shared__ __align__(16) f16x2 h_lds[2][128];    // double-buffered h (f16)
  __shared__ __align__(16) f16x2 x_lds[4][32];     // 4 timesteps of x (f16)
  __shared__ float prA[256], prB[256], prC[256], prD[256]; // half=1 partials
  __shared__ float red[4];

  const int tid  = threadIdx.x;
  const int j    = tid & 255;
  const int half = tid >> 8;
  const int b    = blockIdx.x;

  // stage w_ih into LDS (coalesced)
  for (int n = tid; n < WIH_N; n += 512) wih_lds[n] = wih_p[n];

  // persistent w_hh fragments: 3 gates x 64 f16x2 = 192 VGPRs
  f16x2 w0[64], w1[64], w2[64];
  #pragma unroll
  for (int c = 0; c < 64; ++c) w0[c] = whh_p[((0 + half) * 64 + c) * 256 + j];
  #pragma unroll
  for (int c = 0; c < 64; ++c) w1[c] = whh_p[((2 + half) * 64 + c) * 256 + j];
  #pragma unroll
  for (int c = 0; c < 64; ++c) w2[c] = whh_p[((4 + half) * 64 + c) * 256 + j];

  const float bih0 = b_ih[j], bih1 = b_ih[256 + j], bih2 = b_ih[512 + j];
  const float bhh0 = b_hh[j], bhh1 = b_hh[256 + j], bhh2 = b_hh[512 + j];
  const float wo = w_out[j];
  const float bo = b_out[0];

  float h = 0.0f;
  if (tid < 256) ((_Float16*)h_lds[0])[tid] = (_Float16)0.0f;

  const float* xb = x + (size_t)b * (NT * NI);
  __syncthreads();

  for (int tc = 0; tc < NT / 4; ++tc) {
    // ---- stage x (f16) for 4 timesteps ----
    if (tid < 256) ((_Float16*)x_lds)[tid] = (_Float16)xb[tc * 256 + tid];
    __syncthreads();

    // ---- gi partials for 4 steps: this thread's 32-input slice of 3 gates ----
    float gr[4] = {0, 0, 0, 0}, gz[4] = {0, 0, 0, 0}, gn[4] = {0, 0, 0, 0};
    const float4* wq = (const float4*)wih_lds;
    #pragma unroll
    for (int cqi = 0; cqi < 4; ++cqi) {
      const int cq = half * 4 + cqi;
      float4 A0 = wq[(0 * 8 + cq) * 256 + j];
      float4 A1 = wq[(1 * 8 + cq) * 256 + j];
      float4 A2 = wq[(2 * 8 + cq) * 256 + j];
      f16x2 a0[4] = {__builtin_bit_cast(f16x2, A0.x), __builtin_bit_cast(f16x2, A0.y),
                     __builtin_bit_cast(f16x2, A0.z), __builtin_bit_cast(f16x2, A0.w)};
      f16x2 a1[4] = {__builtin_bit_cast(f16x2, A1.x), __builtin_bit_cast(f16x2, A1.y),
                     __builtin_bit_cast(f16x2, A1.z), __builtin_bit_cast(f16x2, A1.w)};
      f16x2 a2[4] = {__builtin_bit_cast(f16x2, A2.x), __builtin_bit_cast(f16x2, A2.y),
                     __builtin_bit_cast(f16x2, A2.z), __builtin_bit_cast(f16x2, A2.w)};
      #pragma unroll
      for (int k = 0; k < 4; ++k) {
        float4 X = ((const float4*)x_lds[k])[cq];
        f16x2 xv[4] = {__builtin_bit_cast(f16x2, X.x), __builtin_bit_cast(f16x2, X.y),
                       __builtin_bit_cast(f16x2, X.z), __builtin_bit_cast(f16x2, X.w)};
        #pragma unroll
        for (int cc = 0; cc < 4; ++cc) {
          gr[k] = __builtin_amdgcn_fdot2(a0[cc], xv[cc], gr[k], false);
          gz[k] = __builtin_amdgcn_fdot2(a1[cc], xv[cc], gz[k], false);
          gn[k] = __builtin_amdgcn_fdot2(a2[cc], xv[cc], gn[k], false);
        }
      }
    }

    // ---- 4 recurrent steps ----
    #pragma unroll
    for (int k = 0; k < 4; ++k) {
      const int t = tc * 4 + k;
      const float4* hv4 = (const float4*)(h_lds[k & 1] + half * 64);
      float r0 = 0, r1 = 0, z0 = 0, z1 = 0, n0 = 0, n1 = 0;
      #pragma unroll
      for (int m = 0; m < 16; ++m) {
        float4 hv = hv4[m];  // broadcast ds_read_b128
        f16x2 h0 = __builtin_bit_cast(f16x2, hv.x);
        f16x2 h1 = __builtin_bit_cast(f16x2, hv.y);
        f16x2 h2 = __builtin_bit_cast(f16x2, hv.z);
        f16x2 h3 = __builtin_bit_cast(f16x2, hv.w);
        r0 = __builtin_amdgcn_fdot2(w0[4 * m + 0], h0, r0, false);
        z0 = __builtin_amdgcn_fdot2(w1[4 * m + 0], h0, z0, false);
        n0 = __builtin_amdgcn_fdot2(w2[4 * m + 0], h0, n0, false);
        r1 = __builtin_amdgcn_fdot2(w0[4 * m + 1], h1, r1, false);
        z1 = __builtin_amdgcn_fdot2(w1[4 * m + 1], h1, z1, false);
        n1 = __builtin_amdgcn_fdot2(w2[4 * m + 1], h1, n1, false);
        r0 = __builtin_amdgcn_fdot2(w0[4 * m + 2], h2, r0, false);
        z0 = __builtin_amdgcn_fdot2(w1[4 * m + 2], h2, z0, false);
        n0 = __builtin_amdgcn_fdot2(w2[4 * m + 2], h2, n0, false);
        r1 = __builtin_amdgcn_fdot2(w0[4 * m + 3], h3, r1, false);
        z1 = __builtin_amdgcn_fdot2(w1[4 * m + 3], h3, z1, false);
        n1 = __builtin_amdgcn_fdot2(w2[4 * m + 3], h3, n1, false);
      }
      // half=1 publishes its partials; half=0 keeps its own in registers
      if (half) {
        prA[j] = r0 + r1 + gr[k];
        prB[j] = z0 + z1 + gz[k];
        prC[j] = n0 + n1;
        prD[j] = gn[k];
      }
      __syncthreads();
      if (tid < 256) {  // == half 0
        float rr = sigm(bih0 + bhh0 + r0 + r1 + gr[k] + prA[j]);
        float zz = sigm(bih1 + bhh1 + z0 + z1 + gz[k] + prB[j]);
        float nn = tanh_f(bih2 + gn[k] + prD[j] + rr * (bhh2 + n0 + n1 + prC[j]));
        h = (1.0f - zz) * nn + zz * h;
        ((_Float16*)h_lds[(k + 1) & 1])[j] = (_Float16)h;
        // output projection: reduce h*wo over 256 lanes (4 waves)
        float p = h * wo;
        p += __shfl_down(p, 32);
        p += __shfl_down(p, 16);
        p += __shfl_down(p, 8);
        p += __shfl_down(p, 4);
        p += __shfl_down(p, 2);
        p += __shfl_down(p, 1);
        if ((tid & 63) == 0) red[tid >> 6] = p;
      }
      __syncthreads();
      if (tid == 0) out[t * NB + b] = red[0] + red[1] + red[2] + red[3] + bo;
    }
  }
}

extern "C" void kernel_launch(void* const* d_in, const int* in_sizes, int n_in,
                              void* d_out, int out_size, void* d_ws, size_t ws_size,
                              hipStream_t stream) {
  const float* x     = (const float*)d_in[0];
  const float* w_ih  = (const float*)d_in[1];
  const float* w_hh  = (const float*)d_in[2];
  const float* b_ih  = (const float*)d_in[3];
  const float* b_hh  = (const float*)d_in[4];
  const float* w_out = (const float*)d_in[5];
  const float* b_out = (const float*)d_in[6];
  float* out = (float*)d_out;

  f16x2* whh_p = (f16x2*)d_ws;       // 384 KB
  f16x2* wih_p = whh_p + WHH_N;      // 96 KB

  gru_prep_kernel<<<480, 256, 0, stream>>>(w_ih, w_hh, whh_p, wih_p);
  gru_kernel<<<NB, 512, 0, stream>>>(x, b_ih, b_hh, w_out, b_out, whh_p, wih_p, out);
}